// Round 16
// baseline (117.293 us; speedup 1.0000x reference)
//
#include <hip/hip_runtime.h>
#include <type_traits>

typedef float v2f __attribute__((ext_vector_type(2)));

#define BB 2048
#define CC 5
#define TT 2048
#define HH 16
#define OO 2

#define NCH  32           // T-chunks (speculative parallel scan)
#define CHT  (TT / NCH)   // 64 measured steps per chunk
#define WARM 96           // 0.8^96 ~ 5e-10 contraction (absmax-0 proven)

__device__ __forceinline__ float comp4(const float4& v, int j) {
    return j == 0 ? v.x : (j == 1 ? v.y : (j == 2 ? v.z : v.w));
}
__device__ __forceinline__ v2f fma2(v2f a, v2f b, v2f c) {
    return __builtin_elementwise_fma(a, b, c);
}
// pair-swap (quad_perm [1,0,3,2]) + add via DPP builtin (compiler inserts the
// mandatory VALU->DPP wait states; raw asm version failed in R4).
__device__ __forceinline__ float qswap_add(float v) {
    int s = __builtin_amdgcn_update_dpp(0, __float_as_int(v), 0xB1, 0xf, 0xf, true);
    return v + __int_as_float(s);
}

// Fused kernel: one wave per block, 32 b's, h-split-2 (lane pair shares b,
// each lane owns 8 h). LDS is the wave's PRIVATE transpose buffer (single
// wave -> zero barriers). Stage = 16 timesteps of all 5 channels for 32 b's.
__global__ __launch_bounds__(64) void snn_fused_kernel(
    const float* __restrict__ x,
    const float* __restrict__ conv_w,
    const float* __restrict__ conv_b,
    const float* __restrict__ bn_gamma,
    const float* __restrict__ bn_beta,
    const float* __restrict__ bn_mean,
    const float* __restrict__ bn_var,
    const float* __restrict__ fc_w,
    const float* __restrict__ fc_b,
    const float* __restrict__ beta1p,
    const float* __restrict__ beta2p,
    float* __restrict__ out)
{
    // [buf][c][t4][b] : 2*5*4*32*16B = 20KB -> 8 blocks/CU -> 2 waves/SIMD
    __shared__ float4 lds[2][CC][4][32];

    const int lane  = threadIdx.x;
    const int b0    = blockIdx.x * 32;       // block's batch base
    const int bown  = lane >> 1;             // this lane's b (0..31)
    const int hb    = (lane & 1) * 8;        // this lane's h-channel base
    const int chunk = blockIdx.y;

    // staging role: 10 float4 per lane per stage (160 float4 = 32b*5c*4quads)
    const int sbc  = lane >> 2;              // bc sub-index (0..15)
    const int st4  = lane & 3;               // quad index (0..3)

    const float b1 = fminf(fmaxf(beta1p[0], 0.0f), 1.0f);
    const float b2 = fminf(fmaxf(beta2p[0], 0.0f), 1.0f);
    const v2f b1v = {b1, b1};

    // fold conv mid-tap + BN for this lane's 8 h, packed as 4 pairs
    v2f wp[CC][4], effbp[4], fw0p[4], fw1p[4];
#pragma unroll
    for (int hp = 0; hp < 4; ++hp) {
        {
            const int h = hb + 2 * hp;
            const float sc = bn_gamma[h] * rsqrtf(bn_var[h] + 1e-5f);
#pragma unroll
            for (int c = 0; c < CC; ++c)
                wp[c][hp].x = 2.0f * conv_w[h * (CC * 3) + c * 3 + 1] * sc;
            effbp[hp].x = (conv_b[h] - bn_mean[h]) * sc + bn_beta[h];
            fw0p[hp].x = fc_w[h];
            fw1p[hp].x = fc_w[HH + h];
        }
        {
            const int h = hb + 2 * hp + 1;
            const float sc = bn_gamma[h] * rsqrtf(bn_var[h] + 1e-5f);
#pragma unroll
            for (int c = 0; c < CC; ++c)
                wp[c][hp].y = 2.0f * conv_w[h * (CC * 3) + c * 3 + 1] * sc;
            effbp[hp].y = (conv_b[h] - bn_mean[h]) * sc + bn_beta[h];
            fw0p[hp].y = fc_w[h];
            fw1p[hp].y = fc_w[HH + h];
        }
    }
    const float fb0 = fc_b[0], fb1 = fc_b[1];

    const int t_start = chunk * CHT;
    int tw            = t_start - WARM;
    if (tw < 0) tw = 0;
    const int t_end   = t_start + CHT;
    const int S       = (t_end - tw) >> 4;    // 16-step stages: 4/8/10
    const int warmS   = (t_start - tw) >> 4;  // 0/4/6

    v2f mem1p[4] = {}, sp[4] = {};
    float mem2_0 = 0.0f, mem2_1 = 0.0f, s2f0 = 0.0f, s2f1 = 0.0f;
    float acc0 = 0.0f, acc1 = 0.0f;

    // staging registers (statically indexed everywhere — rule #20)
    float4 st[10];

#define STAGE_LOAD(TSB)                                                      \
    {                                                                        \
        _Pragma("unroll")                                                    \
        for (int i = 0; i < 10; ++i) {                                       \
            const int bc = i * 16 + sbc;                                     \
            const int bs = bc & 31, cs = bc >> 5;                            \
            st[i] = *reinterpret_cast<const float4*>(                        \
                x + (size_t)(b0 + bs) * (CC * TT) + (size_t)cs * TT +        \
                (TSB) + st4 * 4);                                            \
        }                                                                    \
    }

#define STAGE_WRITE(BUF)                                                     \
    {                                                                        \
        _Pragma("unroll")                                                    \
        for (int i = 0; i < 10; ++i) {                                       \
            const int bc = i * 16 + sbc;                                     \
            const int bs = bc & 31, cs = bc >> 5;                            \
            lds[BUF][cs][st4][bs] = st[i];                                   \
        }                                                                    \
    }

    auto step4 = [&](const float4 (&cur)[CC], auto ACCC) __attribute__((always_inline)) {
#pragma unroll
        for (int j = 0; j < 4; ++j) {
            v2f xv[CC];
#pragma unroll
            for (int c = 0; c < CC; ++c) {
                const float xs = comp4(cur[c], j);
                xv[c].x = xs; xv[c].y = xs;
            }

            // layer 1 over this lane's 4 h-pairs
            v2f r0p = {0.0f, 0.0f}, r1p = {0.0f, 0.0f};
#pragma unroll
            for (int hp = 0; hp < 4; ++hp) {
                v2f f = effbp[hp];
#pragma unroll
                for (int c = 0; c < CC; ++c)
                    f = fma2(xv[c], wp[c][hp], f);

                const v2f m = fma2(b1v, mem1p[hp], f - sp[hp]);
                mem1p[hp] = m;
                v2f s;
                s.x = m.x > 1.0f ? 1.0f : 0.0f;
                s.y = m.y > 1.0f ? 1.0f : 0.0f;
                sp[hp] = s;
                r0p = fma2(s, fw0p[hp], r0p);
                r1p = fma2(s, fw1p[hp], r1p);
            }
            // in-lane 8h partial, then cross-pair sum (one DPP-add each)
            const float cur2_0 = qswap_add(r0p.x + r0p.y) + fb0;
            const float cur2_1 = qswap_add(r1p.x + r1p.y) + fb1;

            // layer 2 (redundant on both pair-lanes; even lane writes)
            mem2_0 = fmaf(b2, mem2_0, cur2_0 - s2f0);
            s2f0 = mem2_0 > 1.0f ? 1.0f : 0.0f;
            mem2_1 = fmaf(b2, mem2_1, cur2_1 - s2f1);
            s2f1 = mem2_1 > 1.0f ? 1.0f : 0.0f;

            if constexpr (decltype(ACCC)::value) {
                acc0 += s2f0;
                acc1 += s2f1;
            }
        }
    };

    // one stage: issue next loads early, consume current from LDS, write next
#define RUN_STAGE(ACCC)                                                      \
    {                                                                        \
        const bool more = (s + 1 < S);                                       \
        if (more) STAGE_LOAD(tw + (s + 1) * 16);                             \
        _Pragma("unroll")                                                    \
        for (int q4 = 0; q4 < 4; ++q4) {                                     \
            float4 cb[CC];                                                   \
            _Pragma("unroll")                                                \
            for (int c = 0; c < CC; ++c)                                     \
                cb[c] = lds[s & 1][c][q4][bown];                             \
            step4(cb, ACCC);                                                 \
        }                                                                    \
        if (more) STAGE_WRITE((s + 1) & 1);                                  \
    }

    // prologue: stage 0
    STAGE_LOAD(tw);
    STAGE_WRITE(0);

#pragma unroll 1
    for (int s = 0; s < warmS; ++s)
        RUN_STAGE((std::integral_constant<bool, false>{}));
#pragma unroll 1
    for (int s = warmS; s < S; ++s)
        RUN_STAGE((std::integral_constant<bool, true>{}));

#undef RUN_STAGE
#undef STAGE_WRITE
#undef STAGE_LOAD

    if (!(lane & 1)) {
        atomicAdd(&out[(size_t)(b0 + bown) * OO + 0], acc0);  // integer-valued -> exact
        atomicAdd(&out[(size_t)(b0 + bown) * OO + 1], acc1);
    }
}

extern "C" void kernel_launch(void* const* d_in, const int* in_sizes, int n_in,
                              void* d_out, int out_size, void* d_ws, size_t ws_size,
                              hipStream_t stream) {
    const float* x        = (const float*)d_in[0];
    const float* conv_w   = (const float*)d_in[1];
    const float* conv_b   = (const float*)d_in[2];
    const float* bn_gamma = (const float*)d_in[3];
    const float* bn_beta  = (const float*)d_in[4];
    const float* bn_mean  = (const float*)d_in[5];
    const float* bn_var   = (const float*)d_in[6];
    const float* fc_w     = (const float*)d_in[7];
    const float* fc_b     = (const float*)d_in[8];
    const float* beta1    = (const float*)d_in[9];
    const float* beta2    = (const float*)d_in[10];
    float* out = (float*)d_out;

    hipMemsetAsync(out, 0, (size_t)out_size * sizeof(float), stream);

    dim3 grid(BB / 32, NCH);   // 64 x 32 = 2048 single-wave blocks
    snn_fused_kernel<<<grid, dim3(64), 0, stream>>>(
        x, conv_w, conv_b, bn_gamma, bn_beta, bn_mean, bn_var,
        fc_w, fc_b, beta1, beta2, out);
}

// Round 18
// 90.957 us; speedup vs baseline: 1.2895x; 1.2895x over previous
//
#include <hip/hip_runtime.h>
#include <type_traits>

typedef float v2f __attribute__((ext_vector_type(2)));

#define BB 2048
#define CC 5
#define TT 2048
#define HH 16
#define OO 2

#define NCH  32           // T-chunks (speculative parallel scan)
#define CHT  (TT / NCH)   // 64 measured steps per chunk
#define WARM 96           // 0.8^96 ~ 5e-10 contraction (absmax-0 proven)

#define TTL 32            // transpose t-tile
#define BTL 256           // transpose b-tile
#define T4  (TT / 4)
#define XT_BYTES ((size_t)CC * TT * BB * 4)

__device__ __forceinline__ float comp4(const float4& v, int j) {
    return j == 0 ? v.x : (j == 1 ? v.y : (j == 2 ? v.z : v.w));
}
__device__ __forceinline__ v2f fma2(v2f a, v2f b, v2f c) {
    return __builtin_elementwise_fma(a, b, c);
}
__device__ __forceinline__ v2f splat2(float s) {
    v2f r; r.x = s; r.y = s; return r;
}
// ---- VOP3P packed f32 math (inline asm). ALL operands must be 64-bit
// register PAIRS (R17 compile-fail: scalar src0 doesn't encode). Plain VALU,
// no DPP-style hazards.
__device__ __forceinline__ v2f pk_fma(v2f a, v2f b, v2f c) {
    v2f d;
    asm("v_pk_fma_f32 %0, %1, %2, %3"
        : "=v"(d) : "v"(a), "v"(b), "v"(c));
    return d;
}
// d = a - b (packed), via neg modifiers on src1
__device__ __forceinline__ v2f pk_sub(v2f a, v2f b) {
    v2f d;
    asm("v_pk_add_f32 %0, %1, %2 neg_lo:[0,1] neg_hi:[0,1]"
        : "=v"(d) : "v"(a), "v"(b));
    return d;
}
// pair-swap (quad_perm [1,0,3,2]) + add via DPP builtin (compiler inserts the
// mandatory VALU->DPP wait states; raw asm version failed in R4).
__device__ __forceinline__ float qswap_add(float v) {
    int s = __builtin_amdgcn_update_dpp(0, __float_as_int(v), 0xB1, 0xf, 0xf, true);
    return v + __int_as_float(s);
}

// ---------- pre-pass: x[b][c][t] -> xT2[c][t/4][b][4] (t-blocked) ----------
__global__ __launch_bounds__(256) void transpose_kernel(
    const float* __restrict__ x, float* __restrict__ xT2)
{
    __shared__ float tile[TTL][BTL + 1];
    const int c   = blockIdx.z;
    const int tb  = blockIdx.x * TTL;
    const int bb  = blockIdx.y * BTL;
    const int tid = threadIdx.x;

    const int s  = tid & 7;
    const int br = tid >> 3;
#pragma unroll
    for (int i = 0; i < 8; ++i) {
        const int b_local = br + i * 32;
        const float4 v = *reinterpret_cast<const float4*>(
            x + (size_t)(bb + b_local) * (CC * TT) + (size_t)c * TT + tb + 4 * s);
        tile[4 * s + 0][b_local] = v.x;
        tile[4 * s + 1][b_local] = v.y;
        tile[4 * s + 2][b_local] = v.z;
        tile[4 * s + 3][b_local] = v.w;
    }
    __syncthreads();

    float4* xt2v = reinterpret_cast<float4*>(xT2);
#pragma unroll
    for (int t4 = 0; t4 < TTL / 4; ++t4) {
        float4 w;
        w.x = tile[4 * t4 + 0][tid];
        w.y = tile[4 * t4 + 1][tid];
        w.z = tile[4 * t4 + 2][tid];
        w.w = tile[4 * t4 + 3][tid];
        xt2v[((size_t)c * T4 + (tb >> 2) + t4) * BB + bb + tid] = w;
    }
}

// ---------- scan: lane PAIR shares b; each lane owns 8 h-channels ----------
// Plain __launch_bounds__(64): R13's (64,2) capped VGPR at 128 -> full spill.
__global__ __launch_bounds__(64) void snn_scanT2_kernel(
    const float* __restrict__ xT2,
    const float* __restrict__ conv_w,
    const float* __restrict__ conv_b,
    const float* __restrict__ bn_gamma,
    const float* __restrict__ bn_beta,
    const float* __restrict__ bn_mean,
    const float* __restrict__ bn_var,
    const float* __restrict__ fc_w,
    const float* __restrict__ fc_b,
    const float* __restrict__ beta1p,
    const float* __restrict__ beta2p,
    float* __restrict__ out)
{
    const int lane  = threadIdx.x;
    const int b     = blockIdx.x * 32 + (lane >> 1);
    const int hb    = (lane & 1) * 8;        // this lane's h-channel base
    const int chunk = blockIdx.y;

    const float b1 = fminf(fmaxf(beta1p[0], 0.0f), 1.0f);
    const float b2 = fminf(fmaxf(beta2p[0], 0.0f), 1.0f);
    const v2f b1v = splat2(b1);

    // fold conv mid-tap + BN for this lane's 8 h, packed as 4 pairs
    v2f wp[CC][4], effbp[4], fw0p[4], fw1p[4];
#pragma unroll
    for (int hp = 0; hp < 4; ++hp) {
        {
            const int h = hb + 2 * hp;
            const float sc = bn_gamma[h] * rsqrtf(bn_var[h] + 1e-5f);
#pragma unroll
            for (int c = 0; c < CC; ++c)
                wp[c][hp].x = 2.0f * conv_w[h * (CC * 3) + c * 3 + 1] * sc;
            effbp[hp].x = (conv_b[h] - bn_mean[h]) * sc + bn_beta[h];
            fw0p[hp].x = fc_w[h];
            fw1p[hp].x = fc_w[HH + h];
        }
        {
            const int h = hb + 2 * hp + 1;
            const float sc = bn_gamma[h] * rsqrtf(bn_var[h] + 1e-5f);
#pragma unroll
            for (int c = 0; c < CC; ++c)
                wp[c][hp].y = 2.0f * conv_w[h * (CC * 3) + c * 3 + 1] * sc;
            effbp[hp].y = (conv_b[h] - bn_mean[h]) * sc + bn_beta[h];
            fw0p[hp].y = fc_w[h];
            fw1p[hp].y = fc_w[HH + h];
        }
    }
    const float fb0 = fc_b[0], fb1 = fc_b[1];

    const int t_start = chunk * CHT;
    int tw            = t_start - WARM;
    if (tw < 0) tw = 0;
    const int t_end   = t_start + CHT;
    const int ngroups = (t_end - tw) >> 2;     // 16/32/40
    const int warm_g  = (t_start - tw) >> 2;   // 0/16/24

    v2f mem1p[4] = {}, sp[4] = {};
    float mem2_0 = 0.0f, mem2_1 = 0.0f, s2f0 = 0.0f, s2f1 = 0.0f;
    float acc0 = 0.0f, acc1 = 0.0f;

    const float4* xt2v = reinterpret_cast<const float4*>(xT2);

    // ONE float4 per channel per 4-step group (t-blocked layout)
    auto ldg = [&](float4 (&buf)[CC], int t) __attribute__((always_inline)) {
#pragma unroll
        for (int c = 0; c < CC; ++c)
            buf[c] = xt2v[((size_t)c * T4 + (t >> 2)) * BB + b];
    };

    float4 bufA[CC], bufB[CC], bufC[CC], bufD[CC];
    ldg(bufA, tw);
    ldg(bufB, tw + 4);
    ldg(bufC, tw + 8);
    ldg(bufD, tw + 12);

    auto step4 = [&](const float4 (&cur)[CC], auto ACCC) __attribute__((always_inline)) {
#pragma unroll
        for (int j = 0; j < 4; ++j) {
            // splat this step's channel inputs into pairs (1 mov each)
            v2f xv[CC];
#pragma unroll
            for (int c = 0; c < CC; ++c)
                xv[c] = splat2(comp4(cur[c], j));

            // layer 1 over this lane's 4 h-pairs — forced VOP3P packed math.
            // Arithmetic identical to the scalarized form (same fmas, same order).
            v2f r0p = {0.0f, 0.0f}, r1p = {0.0f, 0.0f};
#pragma unroll
            for (int hp = 0; hp < 4; ++hp) {
                v2f f = effbp[hp];
#pragma unroll
                for (int c = 0; c < CC; ++c)
                    f = pk_fma(xv[c], wp[c][hp], f);

                const v2f m = pk_fma(b1v, mem1p[hp], pk_sub(f, sp[hp]));
                mem1p[hp] = m;
                v2f s;
                s.x = m.x > 1.0f ? 1.0f : 0.0f;
                s.y = m.y > 1.0f ? 1.0f : 0.0f;
                sp[hp] = s;
                r0p = pk_fma(s, fw0p[hp], r0p);
                r1p = pk_fma(s, fw1p[hp], r1p);
            }
            // in-lane 8h partial, then cross-pair sum (one DPP-add each)
            const float cur2_0 = qswap_add(r0p.x + r0p.y) + fb0;
            const float cur2_1 = qswap_add(r1p.x + r1p.y) + fb1;

            // layer 2 (redundant on both pair-lanes; even lane writes)
            mem2_0 = fmaf(b2, mem2_0, cur2_0 - s2f0);
            s2f0 = mem2_0 > 1.0f ? 1.0f : 0.0f;
            mem2_1 = fmaf(b2, mem2_1, cur2_1 - s2f1);
            s2f1 = mem2_1 > 1.0f ? 1.0f : 0.0f;

            if constexpr (decltype(ACCC)::value) {
                acc0 += s2f0;
                acc1 += s2f1;
            }
        }
    };

    const int nquads = ngroups >> 2;   // 4/8/10
    const int wquads = warm_g >> 2;    // 0/4/6
    const int tlast  = t_end - 4;

#define RUN_QUAD(ACCC)                                                   \
    {                                                                    \
        int t0 = tw + (4 * q + 4) * 4; if (t0 > tlast) t0 = tlast;       \
        int t1 = tw + (4 * q + 5) * 4; if (t1 > tlast) t1 = tlast;       \
        int t2 = tw + (4 * q + 6) * 4; if (t2 > tlast) t2 = tlast;       \
        int t3 = tw + (4 * q + 7) * 4; if (t3 > tlast) t3 = tlast;       \
        step4(bufA, ACCC); ldg(bufA, t0);                                \
        step4(bufB, ACCC); ldg(bufB, t1);                                \
        step4(bufC, ACCC); ldg(bufC, t2);                                \
        step4(bufD, ACCC); ldg(bufD, t3);                                \
    }

#pragma unroll 1
    for (int q = 0; q < wquads; ++q)
        RUN_QUAD((std::integral_constant<bool, false>{}));
#pragma unroll 1
    for (int q = wquads; q < nquads; ++q)
        RUN_QUAD((std::integral_constant<bool, true>{}));
#undef RUN_QUAD

    if (!(lane & 1)) {
        atomicAdd(&out[(size_t)b * OO + 0], acc0);
        atomicAdd(&out[(size_t)b * OO + 1], acc1);
    }
}

// ---------- fallback (proven R10 kernel, untransposed) ----------
__global__ __launch_bounds__(64, 1) void snn_laneb_fb_kernel(
    const float* __restrict__ x,
    const float* __restrict__ conv_w,
    const float* __restrict__ conv_b,
    const float* __restrict__ bn_gamma,
    const float* __restrict__ bn_beta,
    const float* __restrict__ bn_mean,
    const float* __restrict__ bn_var,
    const float* __restrict__ fc_w,
    const float* __restrict__ fc_b,
    const float* __restrict__ beta1p,
    const float* __restrict__ beta2p,
    float* __restrict__ out)
{
    const int b     = blockIdx.x * 64 + threadIdx.x;
    const int chunk = blockIdx.y;

    const float b1 = fminf(fmaxf(beta1p[0], 0.0f), 1.0f);
    const float b2 = fminf(fmaxf(beta2p[0], 0.0f), 1.0f);
    const v2f b1v = splat2(b1);

    v2f wp[CC][8], effbp[8], fw0p[8], fw1p[8];
#pragma unroll
    for (int hp = 0; hp < 8; ++hp) {
        {
            const int h = 2 * hp;
            const float sc = bn_gamma[h] * rsqrtf(bn_var[h] + 1e-5f);
#pragma unroll
            for (int c = 0; c < CC; ++c)
                wp[c][hp].x = 2.0f * conv_w[h * (CC * 3) + c * 3 + 1] * sc;
            effbp[hp].x = (conv_b[h] - bn_mean[h]) * sc + bn_beta[h];
            fw0p[hp].x = fc_w[h];
            fw1p[hp].x = fc_w[HH + h];
        }
        {
            const int h = 2 * hp + 1;
            const float sc = bn_gamma[h] * rsqrtf(bn_var[h] + 1e-5f);
#pragma unroll
            for (int c = 0; c < CC; ++c)
                wp[c][hp].y = 2.0f * conv_w[h * (CC * 3) + c * 3 + 1] * sc;
            effbp[hp].y = (conv_b[h] - bn_mean[h]) * sc + bn_beta[h];
            fw0p[hp].y = fc_w[h];
            fw1p[hp].y = fc_w[HH + h];
        }
    }
    const float fb0 = fc_b[0], fb1 = fc_b[1];

    const float* xb = x + (size_t)b * CC * TT;

    const int t_start = chunk * CHT;
    int tw            = t_start - WARM;
    if (tw < 0) tw = 0;
    const int t_end   = t_start + CHT;
    const int ngroups = (t_end - tw) >> 2;
    const int warm_g  = (t_start - tw) >> 2;

    v2f mem1p[8] = {}, sp[8] = {};
    float mem2_0 = 0.0f, mem2_1 = 0.0f, s2f0 = 0.0f, s2f1 = 0.0f;
    float acc0 = 0.0f, acc1 = 0.0f;

    auto ldg = [&](float4 (&buf)[CC], int t) __attribute__((always_inline)) {
#pragma unroll
        for (int c = 0; c < CC; ++c)
            buf[c] = *reinterpret_cast<const float4*>(xb + c * TT + t);
    };

    float4 bufA[CC], bufB[CC], bufC[CC], bufD[CC];
    ldg(bufA, tw);
    ldg(bufB, tw + 4);
    ldg(bufC, tw + 8);
    ldg(bufD, tw + 12);

    auto step4 = [&](const float4 (&cur)[CC], auto ACCC) __attribute__((always_inline)) {
#pragma unroll
        for (int j = 0; j < 4; ++j) {
            v2f xv[CC];
#pragma unroll
            for (int c = 0; c < CC; ++c)
                xv[c] = splat2(comp4(cur[c], j));
            v2f r0p = {0.0f, 0.0f}, r1p = {0.0f, 0.0f};
#pragma unroll
            for (int hp = 0; hp < 8; ++hp) {
                v2f f = effbp[hp];
#pragma unroll
                for (int c = 0; c < CC; ++c)
                    f = fma2(xv[c], wp[c][hp], f);
                const v2f m = fma2(b1v, mem1p[hp], f - sp[hp]);
                mem1p[hp] = m;
                v2f s;
                s.x = m.x > 1.0f ? 1.0f : 0.0f;
                s.y = m.y > 1.0f ? 1.0f : 0.0f;
                sp[hp] = s;
                r0p = fma2(s, fw0p[hp], r0p);
                r1p = fma2(s, fw1p[hp], r1p);
            }
            const float cur2_0 = r0p.x + r0p.y + fb0;
            const float cur2_1 = r1p.x + r1p.y + fb1;
            mem2_0 = fmaf(b2, mem2_0, cur2_0 - s2f0);
            s2f0 = mem2_0 > 1.0f ? 1.0f : 0.0f;
            mem2_1 = fmaf(b2, mem2_1, cur2_1 - s2f1);
            s2f1 = mem2_1 > 1.0f ? 1.0f : 0.0f;
            if constexpr (decltype(ACCC)::value) {
                acc0 += s2f0;
                acc1 += s2f1;
            }
        }
    };

    const int nquads = ngroups >> 2;
    const int wquads = warm_g >> 2;
    const int tlast  = t_end - 4;

#define RUN_QUAD(ACCC)                                                   \
    {                                                                    \
        int t0 = tw + (4 * q + 4) * 4; if (t0 > tlast) t0 = tlast;       \
        int t1 = tw + (4 * q + 5) * 4; if (t1 > tlast) t1 = tlast;       \
        int t2 = tw + (4 * q + 6) * 4; if (t2 > tlast) t2 = tlast;       \
        int t3 = tw + (4 * q + 7) * 4; if (t3 > tlast) t3 = tlast;       \
        step4(bufA, ACCC); ldg(bufA, t0);                                \
        step4(bufB, ACCC); ldg(bufB, t1);                                \
        step4(bufC, ACCC); ldg(bufC, t2);                                \
        step4(bufD, ACCC); ldg(bufD, t3);                                \
    }

#pragma unroll 1
    for (int q = 0; q < wquads; ++q)
        RUN_QUAD((std::integral_constant<bool, false>{}));
#pragma unroll 1
    for (int q = wquads; q < nquads; ++q)
        RUN_QUAD((std::integral_constant<bool, true>{}));
#undef RUN_QUAD

    atomicAdd(&out[(size_t)b * OO + 0], acc0);
    atomicAdd(&out[(size_t)b * OO + 1], acc1);
}

extern "C" void kernel_launch(void* const* d_in, const int* in_sizes, int n_in,
                              void* d_out, int out_size, void* d_ws, size_t ws_size,
                              hipStream_t stream) {
    const float* x        = (const float*)d_in[0];
    const float* conv_w   = (const float*)d_in[1];
    const float* conv_b   = (const float*)d_in[2];
    const float* bn_gamma = (const float*)d_in[3];
    const float* bn_beta  = (const float*)d_in[4];
    const float* bn_mean  = (const float*)d_in[5];
    const float* bn_var   = (const float*)d_in[6];
    const float* fc_w     = (const float*)d_in[7];
    const float* fc_b     = (const float*)d_in[8];
    const float* beta1    = (const float*)d_in[9];
    const float* beta2    = (const float*)d_in[10];
    float* out = (float*)d_out;

    hipMemsetAsync(out, 0, (size_t)out_size * sizeof(float), stream);

    if (ws_size >= XT_BYTES) {
        float* xT2 = (float*)d_ws;
        dim3 tgrid(TT / TTL, BB / BTL, CC);
        transpose_kernel<<<tgrid, 256, 0, stream>>>(x, xT2);
        dim3 grid(BB / 32, NCH);           // 64 x 32 = 2048 wg, 2 waves/SIMD
        snn_scanT2_kernel<<<grid, dim3(64), 0, stream>>>(
            xT2, conv_w, conv_b, bn_gamma, bn_beta, bn_mean, bn_var,
            fc_w, fc_b, beta1, beta2, out);
    } else {
        dim3 grid(BB / 64, NCH);
        snn_laneb_fb_kernel<<<grid, dim3(64), 0, stream>>>(
            x, conv_w, conv_b, bn_gamma, bn_beta, bn_mean, bn_var,
            fc_w, fc_b, beta1, beta2, out);
    }
}

// Round 19
// 84.667 us; speedup vs baseline: 1.3853x; 1.0743x over previous
//
#include <hip/hip_runtime.h>
#include <type_traits>

typedef float v2f __attribute__((ext_vector_type(2)));

#define BB 2048
#define CC 5
#define TT 2048
#define HH 16
#define OO 2

#define NCH  32           // T-chunks (speculative parallel scan)
#define CHT  (TT / NCH)   // 64 measured steps per chunk
#define WARM 96           // 0.8^96 ~ 5e-10 contraction (absmax-0 proven)

#define TTL 32            // transpose t-tile
#define BTL 256           // transpose b-tile
#define T4  (TT / 4)
#define XT_BYTES ((size_t)CC * TT * BB * 4)

__device__ __forceinline__ float comp4(const float4& v, int j) {
    return j == 0 ? v.x : (j == 1 ? v.y : (j == 2 ? v.z : v.w));
}
__device__ __forceinline__ v2f fma2(v2f a, v2f b, v2f c) {
    return __builtin_elementwise_fma(a, b, c);
}
// pair-swap (quad_perm [1,0,3,2]) + add via DPP builtin (compiler inserts the
// mandatory VALU->DPP wait states; raw asm version failed in R4).
__device__ __forceinline__ float qswap_add(float v) {
    int s = __builtin_amdgcn_update_dpp(0, __float_as_int(v), 0xB1, 0xf, 0xf, true);
    return v + __int_as_float(s);
}

// ---------- pre-pass: x[b][c][t] -> xT2[c][t/4][b][4] (t-blocked) ----------
__global__ __launch_bounds__(256) void transpose_kernel(
    const float* __restrict__ x, float* __restrict__ xT2)
{
    __shared__ float tile[TTL][BTL + 1];
    const int c   = blockIdx.z;
    const int tb  = blockIdx.x * TTL;
    const int bb  = blockIdx.y * BTL;
    const int tid = threadIdx.x;

    const int s  = tid & 7;
    const int br = tid >> 3;
#pragma unroll
    for (int i = 0; i < 8; ++i) {
        const int b_local = br + i * 32;
        const float4 v = *reinterpret_cast<const float4*>(
            x + (size_t)(bb + b_local) * (CC * TT) + (size_t)c * TT + tb + 4 * s);
        tile[4 * s + 0][b_local] = v.x;
        tile[4 * s + 1][b_local] = v.y;
        tile[4 * s + 2][b_local] = v.z;
        tile[4 * s + 3][b_local] = v.w;
    }
    __syncthreads();

    float4* xt2v = reinterpret_cast<float4*>(xT2);
#pragma unroll
    for (int t4 = 0; t4 < TTL / 4; ++t4) {
        float4 w;
        w.x = tile[4 * t4 + 0][tid];
        w.y = tile[4 * t4 + 1][tid];
        w.z = tile[4 * t4 + 2][tid];
        w.w = tile[4 * t4 + 3][tid];
        xt2v[((size_t)c * T4 + (tb >> 2) + t4) * BB + bb + tid] = w;
    }
}

// ---------- scan: lane PAIR shares b; each lane owns 8 h-channels ----------
// Plain __launch_bounds__(64): R13's (64,2) capped VGPR at 128 -> full spill.
// Layer-2 split (R19): even lane owns output 0, odd lane owns output 1 —
// per-output arithmetic identical to the redundant form (absmax-0 proven).
__global__ __launch_bounds__(64) void snn_scanT2_kernel(
    const float* __restrict__ xT2,
    const float* __restrict__ conv_w,
    const float* __restrict__ conv_b,
    const float* __restrict__ bn_gamma,
    const float* __restrict__ bn_beta,
    const float* __restrict__ bn_mean,
    const float* __restrict__ bn_var,
    const float* __restrict__ fc_w,
    const float* __restrict__ fc_b,
    const float* __restrict__ beta1p,
    const float* __restrict__ beta2p,
    float* __restrict__ out)
{
    const int lane  = threadIdx.x;
    const int b     = blockIdx.x * 32 + (lane >> 1);
    const int odd   = lane & 1;
    const int hb    = odd * 8;               // this lane's h-channel base
    const int chunk = blockIdx.y;

    const float b1 = fminf(fmaxf(beta1p[0], 0.0f), 1.0f);
    const float b2 = fminf(fmaxf(beta2p[0], 0.0f), 1.0f);
    const v2f b1v = {b1, b1};

    // fold conv mid-tap + BN for this lane's 8 h, packed as 4 pairs
    v2f wp[CC][4], effbp[4], fw0p[4], fw1p[4];
#pragma unroll
    for (int hp = 0; hp < 4; ++hp) {
        {
            const int h = hb + 2 * hp;
            const float sc = bn_gamma[h] * rsqrtf(bn_var[h] + 1e-5f);
#pragma unroll
            for (int c = 0; c < CC; ++c)
                wp[c][hp].x = 2.0f * conv_w[h * (CC * 3) + c * 3 + 1] * sc;
            effbp[hp].x = (conv_b[h] - bn_mean[h]) * sc + bn_beta[h];
            fw0p[hp].x = fc_w[h];
            fw1p[hp].x = fc_w[HH + h];
        }
        {
            const int h = hb + 2 * hp + 1;
            const float sc = bn_gamma[h] * rsqrtf(bn_var[h] + 1e-5f);
#pragma unroll
            for (int c = 0; c < CC; ++c)
                wp[c][hp].y = 2.0f * conv_w[h * (CC * 3) + c * 3 + 1] * sc;
            effbp[hp].y = (conv_b[h] - bn_mean[h]) * sc + bn_beta[h];
            fw0p[hp].y = fc_w[h];
            fw1p[hp].y = fc_w[HH + h];
        }
    }
    const float fbv = odd ? fc_b[1] : fc_b[0];   // this lane's output bias

    const int t_start = chunk * CHT;
    int tw            = t_start - WARM;
    if (tw < 0) tw = 0;
    const int t_end   = t_start + CHT;
    const int ngroups = (t_end - tw) >> 2;     // 16/32/40
    const int warm_g  = (t_start - tw) >> 2;   // 0/16/24

    v2f mem1p[4] = {}, sp[4] = {};
    float mem2v = 0.0f, s2v = 0.0f, accv = 0.0f;

    const float4* xt2v = reinterpret_cast<const float4*>(xT2);

    // ONE float4 per channel per 4-step group (t-blocked layout)
    auto ldg = [&](float4 (&buf)[CC], int t) __attribute__((always_inline)) {
#pragma unroll
        for (int c = 0; c < CC; ++c)
            buf[c] = xt2v[((size_t)c * T4 + (t >> 2)) * BB + b];
    };

    float4 bufA[CC], bufB[CC], bufC[CC], bufD[CC];
    ldg(bufA, tw);
    ldg(bufB, tw + 4);
    ldg(bufC, tw + 8);
    ldg(bufD, tw + 12);

    auto step4 = [&](const float4 (&cur)[CC], auto ACCC) __attribute__((always_inline)) {
#pragma unroll
        for (int j = 0; j < 4; ++j) {
            v2f xv[CC];
#pragma unroll
            for (int c = 0; c < CC; ++c) {
                const float xs = comp4(cur[c], j);
                xv[c].x = xs; xv[c].y = xs;
            }

            // layer 1 over this lane's 4 h-pairs
            v2f r0p = {0.0f, 0.0f}, r1p = {0.0f, 0.0f};
#pragma unroll
            for (int hp = 0; hp < 4; ++hp) {
                v2f f = effbp[hp];
#pragma unroll
                for (int c = 0; c < CC; ++c)
                    f = fma2(xv[c], wp[c][hp], f);

                const v2f m = fma2(b1v, mem1p[hp], f - sp[hp]);
                mem1p[hp] = m;
                v2f s;
                s.x = m.x > 1.0f ? 1.0f : 0.0f;
                s.y = m.y > 1.0f ? 1.0f : 0.0f;
                sp[hp] = s;
                r0p = fma2(s, fw0p[hp], r0p);
                r1p = fma2(s, fw1p[hp], r1p);
            }
            // cross-pair totals (both computed on all lanes; each lane uses one)
            const float tot0 = qswap_add(r0p.x + r0p.y);
            const float tot1 = qswap_add(r1p.x + r1p.y);
            const float cur2 = (odd ? tot1 : tot0) + fbv;

            // layer 2: ONE chain per lane (even->out0, odd->out1)
            mem2v = fmaf(b2, mem2v, cur2 - s2v);
            s2v = mem2v > 1.0f ? 1.0f : 0.0f;

            if constexpr (decltype(ACCC)::value) {
                accv += s2v;
            }
        }
    };

    const int nquads = ngroups >> 2;   // 4/8/10
    const int wquads = warm_g >> 2;    // 0/4/6
    const int tlast  = t_end - 4;

#define RUN_QUAD(ACCC)                                                   \
    {                                                                    \
        int t0 = tw + (4 * q + 4) * 4; if (t0 > tlast) t0 = tlast;       \
        int t1 = tw + (4 * q + 5) * 4; if (t1 > tlast) t1 = tlast;       \
        int t2 = tw + (4 * q + 6) * 4; if (t2 > tlast) t2 = tlast;       \
        int t3 = tw + (4 * q + 7) * 4; if (t3 > tlast) t3 = tlast;       \
        step4(bufA, ACCC); ldg(bufA, t0);                                \
        step4(bufB, ACCC); ldg(bufB, t1);                                \
        step4(bufC, ACCC); ldg(bufC, t2);                                \
        step4(bufD, ACCC); ldg(bufD, t3);                                \
    }

#pragma unroll 1
    for (int q = 0; q < wquads; ++q)
        RUN_QUAD((std::integral_constant<bool, false>{}));
#pragma unroll 1
    for (int q = wquads; q < nquads; ++q)
        RUN_QUAD((std::integral_constant<bool, true>{}));
#undef RUN_QUAD

    // every lane owns exactly one output element
    atomicAdd(&out[(size_t)b * OO + odd], accv);
}

// ---------- fallback (proven R10 kernel, untransposed) ----------
__global__ __launch_bounds__(64, 1) void snn_laneb_fb_kernel(
    const float* __restrict__ x,
    const float* __restrict__ conv_w,
    const float* __restrict__ conv_b,
    const float* __restrict__ bn_gamma,
    const float* __restrict__ bn_beta,
    const float* __restrict__ bn_mean,
    const float* __restrict__ bn_var,
    const float* __restrict__ fc_w,
    const float* __restrict__ fc_b,
    const float* __restrict__ beta1p,
    const float* __restrict__ beta2p,
    float* __restrict__ out)
{
    const int b     = blockIdx.x * 64 + threadIdx.x;
    const int chunk = blockIdx.y;

    const float b1 = fminf(fmaxf(beta1p[0], 0.0f), 1.0f);
    const float b2 = fminf(fmaxf(beta2p[0], 0.0f), 1.0f);
    const v2f b1v = {b1, b1};

    v2f wp[CC][8], effbp[8], fw0p[8], fw1p[8];
#pragma unroll
    for (int hp = 0; hp < 8; ++hp) {
        {
            const int h = 2 * hp;
            const float sc = bn_gamma[h] * rsqrtf(bn_var[h] + 1e-5f);
#pragma unroll
            for (int c = 0; c < CC; ++c)
                wp[c][hp].x = 2.0f * conv_w[h * (CC * 3) + c * 3 + 1] * sc;
            effbp[hp].x = (conv_b[h] - bn_mean[h]) * sc + bn_beta[h];
            fw0p[hp].x = fc_w[h];
            fw1p[hp].x = fc_w[HH + h];
        }
        {
            const int h = 2 * hp + 1;
            const float sc = bn_gamma[h] * rsqrtf(bn_var[h] + 1e-5f);
#pragma unroll
            for (int c = 0; c < CC; ++c)
                wp[c][hp].y = 2.0f * conv_w[h * (CC * 3) + c * 3 + 1] * sc;
            effbp[hp].y = (conv_b[h] - bn_mean[h]) * sc + bn_beta[h];
            fw0p[hp].y = fc_w[h];
            fw1p[hp].y = fc_w[HH + h];
        }
    }
    const float fb0 = fc_b[0], fb1 = fc_b[1];

    const float* xb = x + (size_t)b * CC * TT;

    const int t_start = chunk * CHT;
    int tw            = t_start - WARM;
    if (tw < 0) tw = 0;
    const int t_end   = t_start + CHT;
    const int ngroups = (t_end - tw) >> 2;
    const int warm_g  = (t_start - tw) >> 2;

    v2f mem1p[8] = {}, sp[8] = {};
    float mem2_0 = 0.0f, mem2_1 = 0.0f, s2f0 = 0.0f, s2f1 = 0.0f;
    float acc0 = 0.0f, acc1 = 0.0f;

    auto ldg = [&](float4 (&buf)[CC], int t) __attribute__((always_inline)) {
#pragma unroll
        for (int c = 0; c < CC; ++c)
            buf[c] = *reinterpret_cast<const float4*>(xb + c * TT + t);
    };

    float4 bufA[CC], bufB[CC], bufC[CC], bufD[CC];
    ldg(bufA, tw);
    ldg(bufB, tw + 4);
    ldg(bufC, tw + 8);
    ldg(bufD, tw + 12);

    auto step4 = [&](const float4 (&cur)[CC], auto ACCC) __attribute__((always_inline)) {
#pragma unroll
        for (int j = 0; j < 4; ++j) {
            v2f xv[CC];
#pragma unroll
            for (int c = 0; c < CC; ++c) {
                const float xs = comp4(cur[c], j);
                xv[c].x = xs; xv[c].y = xs;
            }
            v2f r0p = {0.0f, 0.0f}, r1p = {0.0f, 0.0f};
#pragma unroll
            for (int hp = 0; hp < 8; ++hp) {
                v2f f = effbp[hp];
#pragma unroll
                for (int c = 0; c < CC; ++c)
                    f = fma2(xv[c], wp[c][hp], f);
                const v2f m = fma2(b1v, mem1p[hp], f - sp[hp]);
                mem1p[hp] = m;
                v2f s;
                s.x = m.x > 1.0f ? 1.0f : 0.0f;
                s.y = m.y > 1.0f ? 1.0f : 0.0f;
                sp[hp] = s;
                r0p = fma2(s, fw0p[hp], r0p);
                r1p = fma2(s, fw1p[hp], r1p);
            }
            const float cur2_0 = r0p.x + r0p.y + fb0;
            const float cur2_1 = r1p.x + r1p.y + fb1;
            mem2_0 = fmaf(b2, mem2_0, cur2_0 - s2f0);
            s2f0 = mem2_0 > 1.0f ? 1.0f : 0.0f;
            mem2_1 = fmaf(b2, mem2_1, cur2_1 - s2f1);
            s2f1 = mem2_1 > 1.0f ? 1.0f : 0.0f;
            if constexpr (decltype(ACCC)::value) {
                acc0 += s2f0;
                acc1 += s2f1;
            }
        }
    };

    const int nquads = ngroups >> 2;
    const int wquads = warm_g >> 2;
    const int tlast  = t_end - 4;

#define RUN_QUAD(ACCC)                                                   \
    {                                                                    \
        int t0 = tw + (4 * q + 4) * 4; if (t0 > tlast) t0 = tlast;       \
        int t1 = tw + (4 * q + 5) * 4; if (t1 > tlast) t1 = tlast;       \
        int t2 = tw + (4 * q + 6) * 4; if (t2 > tlast) t2 = tlast;       \
        int t3 = tw + (4 * q + 7) * 4; if (t3 > tlast) t3 = tlast;       \
        step4(bufA, ACCC); ldg(bufA, t0);                                \
        step4(bufB, ACCC); ldg(bufB, t1);                                \
        step4(bufC, ACCC); ldg(bufC, t2);                                \
        step4(bufD, ACCC); ldg(bufD, t3);                                \
    }

#pragma unroll 1
    for (int q = 0; q < wquads; ++q)
        RUN_QUAD((std::integral_constant<bool, false>{}));
#pragma unroll 1
    for (int q = wquads; q < nquads; ++q)
        RUN_QUAD((std::integral_constant<bool, true>{}));
#undef RUN_QUAD

    atomicAdd(&out[(size_t)b * OO + 0], acc0);
    atomicAdd(&out[(size_t)b * OO + 1], acc1);
}

extern "C" void kernel_launch(void* const* d_in, const int* in_sizes, int n_in,
                              void* d_out, int out_size, void* d_ws, size_t ws_size,
                              hipStream_t stream) {
    const float* x        = (const float*)d_in[0];
    const float* conv_w   = (const float*)d_in[1];
    const float* conv_b   = (const float*)d_in[2];
    const float* bn_gamma = (const float*)d_in[3];
    const float* bn_beta  = (const float*)d_in[4];
    const float* bn_mean  = (const float*)d_in[5];
    const float* bn_var   = (const float*)d_in[6];
    const float* fc_w     = (const float*)d_in[7];
    const float* fc_b     = (const float*)d_in[8];
    const float* beta1    = (const float*)d_in[9];
    const float* beta2    = (const float*)d_in[10];
    float* out = (float*)d_out;

    hipMemsetAsync(out, 0, (size_t)out_size * sizeof(float), stream);

    if (ws_size >= XT_BYTES) {
        float* xT2 = (float*)d_ws;
        dim3 tgrid(TT / TTL, BB / BTL, CC);
        transpose_kernel<<<tgrid, 256, 0, stream>>>(x, xT2);
        dim3 grid(BB / 32, NCH);           // 64 x 32 = 2048 wg, 2 waves/SIMD
        snn_scanT2_kernel<<<grid, dim3(64), 0, stream>>>(
            xT2, conv_w, conv_b, bn_gamma, bn_beta, bn_mean, bn_var,
            fc_w, fc_b, beta1, beta2, out);
    } else {
        dim3 grid(BB / 64, NCH);
        snn_laneb_fb_kernel<<<grid, dim3(64), 0, stream>>>(
            x, conv_w, conv_b, bn_gamma, bn_beta, bn_mean, bn_var,
            fc_w, fc_b, beta1, beta2, out);
    }
}